// Round 12
// baseline (190.911 us; speedup 1.0000x reference)
//
#include <hip/hip_runtime.h>

// CARAFE++ (B=4, C=256, H=W=64, SCALE=2, K=5, G=1, MID=64, ENC_OUT=100). FP32 I/O.
// R17: 184.9us (noise band ±5 vs R15 177.4 — gather UNCHANGED yet 43.6->47).
//   gather now top: 47us, VALU 39%, conflicts 0. LDS pipe = 12800 wave-b32/CU
//   x 5.8cyc = 31us critical path; 5-tap windows read scalar b32 because odd-j
//   threads can't use aligned b64.
// R18: gather parity-dual-copy: stage rows twice (O copy shifted 1 float);
//   thread picks copy by j-parity -> every window = 3x ds_read_b64 (f32x2),
//   taps = free register extracts. 8-ch blocks (grid 8192) keep LDS 21.8KB
//   (7 blocks/CU). Wave LDS instrs 12800->7680/CU (~21us pipe). enc/compress
//   untouched (R16 enc kept: structural read-halving is sound, noise hides it).
//
// ws layout (float offsets):
#define OFF_FEAT 0              // feat [b][pix][m=64]             1,048,576 f
#define OFF_WET  1048576        // W_enc^T [m*9+rs][p*32+kk]          73,728 f
#define OFF_WCT  1122304        // W_comp^T [c][m]                    16,384 f
#define OFF_WK   1138688        // wk2 [p*25+k][b*4096+pix]        1,638,400 f
#define WS_FLOATS 2777088       // = 11,108,352 bytes

using f32x2 = __attribute__((ext_vector_type(2))) float;

// ---------------- prep: weight transposes ----------------
__global__ __launch_bounds__(256) void prep_kernel(
    const float* __restrict__ Wc, const float* __restrict__ We,
    float* __restrict__ ws) {
    int i = blockIdx.x * 256 + threadIdx.x;
    if (i < 16384) {                       // WcT[c*64+m] = Wc[m][c]
        int c = i >> 6, m = i & 63;
        ws[OFF_WCT + i] = Wc[m * 256 + c];
    }
    if (i < 73728) {                       // Wet[(m*9+rs)*128 + p*32 + kk]
        int mrs = i >> 7, rem = i & 127;
        int p = rem >> 5, kk = rem & 31;
        ws[OFF_WET + i] = (kk < 25) ? We[(p * 25 + kk) * 576 + mrs] : 0.f;
    }
}

// ---------------- K1: 1x1 compress conv + relu ----------------
// grid 1024 x 256 thr = 4 waves/block, wave = 4 px, lane = m.
// Per c: 1 coalesced w-load (VGPR) + 1 uniform float4 x-read (SGPR) + 2 pk-FMA.
__global__ __launch_bounds__(256) void compress_kernel(
    const float* __restrict__ x, const float* __restrict__ bc,
    const float* __restrict__ ws, float* __restrict__ feat) {
    int t = threadIdx.x;
    int lane = t & 63;                               // = m
    int px0 = __builtin_amdgcn_readfirstlane((blockIdx.x << 4) + ((t >> 6) << 2));
    int b = px0 >> 12, pl = px0 & 4095;
    const float* wct = ws + OFF_WCT;                 // [c][64 m]
    const float* xw = x + (((size_t)(b * 256)) << 12) + pl;   // wave-uniform
    f32x2 a01 = {0.f, 0.f}, a23 = {0.f, 0.f};
#pragma unroll 4
    for (int c = 0; c < 256; c++) {
        float w = wct[(c << 6) + lane];              // coalesced, L2-hot
        const float4 xv = *(const float4*)(xw + ((size_t)c << 12));  // uniform
        a01 += (f32x2){xv.x, xv.y} * w;
        a23 += (f32x2){xv.z, xv.w} * w;
    }
    float bv = bc[lane];
    float v0 = a01.x + bv, v1 = a01.y + bv, v2 = a23.x + bv, v3 = a23.y + bv;
    float* fp = feat + (((size_t)((b << 12) + pl)) << 6) + lane;  // [pix][m]
    fp[0]   = v0 > 0.f ? v0 : 0.f;                   // coalesced over m
    fp[64]  = v1 > 0.f ? v1 : 0.f;
    fp[128] = v2 > 0.f ? v2 : 0.f;
    fp[192] = v3 > 0.f ? v3 : 0.f;
}

// ---------------- K2: 3x3 enc conv + bias + softmax(25) ----------------
// grid 512 = (b x 8x8 tile) x 2 p-pairs. 512 thr = 64 px x (2pp x 2kg x 2mg).
// q=16 kk-slice (2x s_load-wide), HALF the m per thread -> half the ds_reads.
// mg partials merged in LDS (stride-65, conflict-free); bias at merge.
__global__ __launch_bounds__(512, 4) void enc_kernel(
    const float* __restrict__ be, const float* __restrict__ ws,
    float* __restrict__ wkout) {
    __shared__ float fs[4224];   // halo [32m][121]=3872 / merged logits [64px][65]
    int t = threadIdx.x;
    int blk = blockIdx.x;
    int tile = blk >> 1, ph2 = blk & 1;    // p-pair index
    int b = tile >> 6, t6 = tile & 63;
    int i0 = (t6 >> 3) << 3, j0 = (t6 & 7) << 3;
    int pix = t & 63;
    int li = pix >> 3, lj = pix & 7;
    int g = __builtin_amdgcn_readfirstlane(t >> 6);  // 0..7, wave-uniform
    int pp = (g >> 2) & 1;                           // p within pair
    int kg = (g >> 1) & 1;                           // kk half: k0 = kg*16
    int mg = g & 1;                                  // m half within phase
    int p = (ph2 << 1) | pp;
    int k0 = kg << 4;
    const float* feat = ws + OFF_FEAT;               // [b][pix][64 m]
    const float* wet = ws + OFF_WET + p * 32 + k0;   // uniform, 64B-aligned

    f32x2 acc2[8];
#pragma unroll
    for (int q = 0; q < 8; q++) acc2[q] = (f32x2){0.f, 0.f};

    for (int phase = 0; phase < 2; phase++) {
        int mb = phase << 5;
        for (int idx = t; idx < 3200; idx += 512) {  // stage 32-m halo (0-padded)
            int m = idx & 31, pos = idx >> 5;        // lanes: consecutive m
            int r = pos / 10, s = pos - r * 10;
            int gi = i0 + r - 1, gj = j0 + s - 1;
            float v = 0.f;
            if ((unsigned)gi < 64u && (unsigned)gj < 64u)
                v = feat[(((size_t)((b << 12) + (gi << 6) + gj)) << 6) + mb + m];
            fs[m * 121 + r * 12 + s] = v;            // stride-121: conflict-free
        }
        __syncthreads();

        int m0 = mg << 4;                            // this thread's m half
#pragma unroll 2
        for (int m = m0; m < m0 + 16; m++) {
            const float* fb = fs + m * 121 + li * 12 + lj;
            float f9[9];
#pragma unroll
            for (int r = 0; r < 3; r++)
#pragma unroll
                for (int s = 0; s < 3; s++) f9[r * 3 + s] = fb[r * 12 + s];
            const float* wrow = wet + (mb + m) * 1152;   // uniform -> s_load_dwordx16
#pragma unroll
            for (int rs = 0; rs < 9; rs++) {
                float f = f9[rs];
                const f32x2* w2 = (const f32x2*)(wrow + rs * 128);  // 16 kk slice
#pragma unroll
                for (int q = 0; q < 8; q++) acc2[q] += f * w2[q];
            }
        }
        __syncthreads();                             // reads done before re-stage
    }

    // merge mg halves: region fs[pix*65 + pp*32 + kg*16 + q] (stride 65 = c-free)
    int red = pix * 65 + (pp << 5) + k0;
    if (mg == 0) {
#pragma unroll
        for (int q = 0; q < 8; q++) {
            fs[red + 2 * q]     = acc2[q].x;
            fs[red + 2 * q + 1] = acc2[q].y;
        }
    }
    __syncthreads();
    if (mg == 1) {                                   // total + bias (k>=25 garbage)
#pragma unroll
        for (int q = 0; q < 8; q++) {
            int k = k0 + 2 * q;
            if (k < 25)     fs[red + 2 * q]     += acc2[q].x + be[p * 25 + k];
            if (k + 1 < 25) fs[red + 2 * q + 1] += acc2[q].y + be[p * 25 + k + 1];
        }
    }
    __syncthreads();

    if (t < 128) {                                   // softmax: thread = (pp, pixel)
        int sp = t >> 6, spx = t & 63;
        const float* lg = fs + spx * 65 + (sp << 5); // merged row, k = 0..24 direct
        float sv[25], mx = -1e30f;
#pragma unroll
        for (int k = 0; k < 25; k++) { sv[k] = lg[k]; mx = fmaxf(mx, sv[k]); }
        float s = 0.f;
#pragma unroll
        for (int k = 0; k < 25; k++) { sv[k] = __expf(sv[k] - mx); s += sv[k]; }
        float inv = 1.f / s;
        int preal = (ph2 << 1) | sp;
        int pgl = ((i0 + (spx >> 3)) << 6) + j0 + (spx & 7);
        float* wp = wkout + (preal * 25) * 16384 + (b << 12) + pgl;
#pragma unroll
        for (int k = 0; k < 25; k++) wp[k * 16384] = sv[k] * inv;  // coalesced
    }
}

// ---------------- K3: gather + pixel rearrange ----------------
// grid 8192 = (b*64+i)*32 + cc(8 ch). 256 thr = 64 j x (2 ph x 2 ch), 4 c2 each.
// Parity-dual staging: copy E (as before) + copy O shifted 1 float. Thread
// reads 3x ds_read_b64 per (c,dy) window from parity-matched copy; taps are
// free register extracts. Wave LDS instrs 200 b32 -> 60 b64.
__global__ __launch_bounds__(256) void gather_kernel(
    const float* __restrict__ x, const float* __restrict__ ws,
    float* __restrict__ out) {
    __shared__ __align__(16) float xs[2 * 8 * 5 * 68];   // E at 0, O at 2720; 21.76 KB
    int t = threadIdx.x;
    int blk = blockIdx.x;
    int cc = blk & 31;                               // 8-channel slab
    int bi = blk >> 5;
    int b = bi >> 6, i = bi & 63;
    int j = t & 63;
    int g = t >> 6;                                  // wave id: 0..3
    int ph = g >> 1, ch = g & 1;                     // p-pair, c-parity

    // coalesced wk loads: wk2[(p*25+k)*16384 + b*4096 + i*64 + j]
    f32x2 w01[25];
    {
        const float* wp = ws + OFF_WK + (ph * 50) * 16384 + (b << 12) + (i << 6) + j;
#pragma unroll
        for (int k = 0; k < 25; k++) {
            w01[k].x = wp[k * 16384];
            w01[k].y = wp[(25 + k) * 16384];
        }
    }

    // stage 8 c x 5 dy rows, two copies (E: +2 pad; O: shifted, o[w]=e[w+1]).
    {
        int lane = t & 63, cd0 = t >> 6;             // 40 rows, 4 at a time
        for (int cd = cd0; cd < 40; cd += 4) {
            int c = cd / 5, dy = cd - c * 5;
            int gi = i - 2 + dy;
            float v = 0.f;
            if ((unsigned)gi < 64u)
                v = x[((b * 256 + (cc << 3) + c) << 12) + (gi << 6) + lane];
            float* re = xs + cd * 68;                // E copy
            float* ro = xs + 2720 + cd * 68;         // O copy
            re[2 + lane] = v;
            ro[1 + lane] = v;
            if (lane < 2)  re[lane] = 0.f;           // e[0..1] = 0
            if (lane == 0) ro[0] = 0.f;              // o[0] = e[1] = 0
            if (lane >= 62) re[lane + 4] = 0.f;      // e[66..67] = 0
            if (lane >= 61) ro[lane + 4] = 0.f;      // o[65..67] = 0
        }
    }
    __syncthreads();

    int sel = j & 1;
    const float* xrow = xs + sel * 2720 + (j - sel); // parity-matched, 8B-aligned
    for (int cq = 0; cq < 4; cq++) {
        int c2 = ch + (cq << 1);                     // c-parity split over 8 ch
        const float* cb = xrow + (c2 * 5) * 68;
        f32x2 a2 = {0.f, 0.f};
#pragma unroll
        for (int dy = 0; dy < 5; dy++) {
            const f32x2* q = (const f32x2*)(cb + dy * 68);   // even float offset
            f32x2 v0 = q[0], v1 = q[1], v2 = q[2];   // taps j+0..j+5 (use 5)
            a2 += v0.x * w01[dy * 5 + 0];
            a2 += v0.y * w01[dy * 5 + 1];
            a2 += v1.x * w01[dy * 5 + 2];
            a2 += v1.y * w01[dy * 5 + 3];
            a2 += v2.x * w01[dy * 5 + 4];
        }
        int c = (cc << 3) + c2;
        *(float2*)(out + (((b * 256 + c) << 12) + (i << 6) + j) * 4 + ph * 2) =
            make_float2(a2.x, a2.y);
    }
}

// ---------------- fallback: round-3 fused kernel (correct, slow) ----------------
__global__ __launch_bounds__(512) void carafe_fused(
    const float* __restrict__ x, const float* __restrict__ Wc,
    const float* __restrict__ bc, const float* __restrict__ We,
    const float* __restrict__ be, float* __restrict__ out) {
    __shared__ float xs[32 * 144];
    __shared__ float fw[6656];
    __shared__ float wst[3600];
    const int t = threadIdx.x;
    const int blk = blockIdx.x;
    const int b = blk >> 6, tile = blk & 63;
    const int i0 = (tile >> 3) << 3, j0 = (tile & 7) << 3;
    const int wid = t >> 6, pix = t & 63;
    const int li = pix >> 3, lj = pix & 7;
    float facc[13];
#pragma unroll
    for (int q = 0; q < 13; q++) facc[q] = 0.f;
    for (int cc = 0; cc < 8; cc++) {
        for (int idx = t; idx < 32 * 144; idx += 512) {
            int c = idx / 144, pos = idx - c * 144;
            int r = pos / 12, u = pos - r * 12;
            int gi = i0 + r - 2, gj = j0 + u - 2;
            float v = 0.f;
            if ((unsigned)gi < 64u && (unsigned)gj < 64u)
                v = x[(((b * 256 + cc * 32 + c) << 12) + (gi << 6) + gj)];
            xs[idx] = v;
        }
        __syncthreads();
#pragma unroll
        for (int q = 0; q < 13; q++) {
            int idx = q * 512 + t;
            if (idx < 6400) {
                int m = idx / 100, pos = idx - m * 100;
                int fi = pos / 10, fj = pos - fi * 10;
                int tp = (fi + 1) * 12 + fj + 1;
                const float* wr = Wc + m * 256 + cc * 32;
                float a = facc[q];
                for (int c = 0; c < 32; c++) a += xs[c * 144 + tp] * wr[c];
                facc[q] = a;
            }
        }
        __syncthreads();
    }
#pragma unroll
    for (int q = 0; q < 13; q++) {
        int idx = q * 512 + t;
        if (idx < 6400) {
            int m = idx / 100, pos = idx - m * 100;
            int fi = pos / 10, fj = pos - fi * 10;
            int gi = i0 + fi - 1, gj = j0 + fj - 1;
            float v = facc[q] + bc[m];
            v = v > 0.f ? v : 0.f;
            if ((unsigned)gi >= 64u || (unsigned)gj >= 64u) v = 0.f;
            fw[idx] = v;
        }
    }
    float acc[13];
#pragma unroll
    for (int q = 0; q < 13; q++) acc[q] = 0.f;
    for (int mb = 0; mb < 16; mb++) {
        for (int idx = t; idx < 3600; idx += 512) {
            int mm = idx / 900, rem = idx - mm * 900;
            int o = rem / 9, rs = rem - o * 9;
            wst[idx] = We[o * 576 + (mb * 4 + mm) * 9 + rs];
        }
        __syncthreads();
#pragma unroll
        for (int mm = 0; mm < 4; mm++) {
            const float* fb = fw + (mb * 4 + mm) * 100 + li * 10 + lj;
            float f9[9];
#pragma unroll
            for (int r = 0; r < 3; r++)
#pragma unroll
                for (int s = 0; s < 3; s++) f9[r * 3 + s] = fb[r * 10 + s];
#pragma unroll
            for (int q = 0; q < 13; q++) {
                int o = q * 8 + wid;
                if (o < 100) {
                    const float* wr = wst + mm * 900 + o * 9;
                    float a = acc[q];
#pragma unroll
                    for (int rs = 0; rs < 9; rs++) a += f9[rs] * wr[rs];
                    acc[q] = a;
                }
            }
        }
        __syncthreads();
    }
#pragma unroll
    for (int q = 0; q < 13; q++) {
        int o = q * 8 + wid;
        if (o < 100) fw[pix * 104 + o] = acc[q];
    }
    __syncthreads();
    float sv[25];
    float inv = 0.f;
    const int sp = t >> 6, spx = t & 63;
    const bool act = (t < 256);
    if (act) {
        float mx = -1e30f;
#pragma unroll
        for (int k = 0; k < 25; k++) {
            sv[k] = fw[spx * 104 + sp * 25 + k] + be[sp * 25 + k];
            mx = fmaxf(mx, sv[k]);
        }
        float s = 0.f;
#pragma unroll
        for (int k = 0; k < 25; k++) { sv[k] = __expf(sv[k] - mx); s += sv[k]; }
        inv = 1.f / s;
    }
    __syncthreads();
    if (act) {
#pragma unroll
        for (int k = 0; k < 25; k++) fw[spx * 104 + k * 4 + sp] = sv[k] * inv;
    }
    __syncthreads();
    float w[25][4];
    const float4* wp = (const float4*)(fw + pix * 104);
#pragma unroll
    for (int k = 0; k < 25; k++) {
        float4 ww = wp[k];
        w[k][0] = ww.x; w[k][1] = ww.y; w[k][2] = ww.z; w[k][3] = ww.w;
    }
    const int pgl = ((i0 + li) << 6) + (j0 + lj);
    for (int cc = 0; cc < 8; cc++) {
        for (int idx = t; idx < 32 * 144; idx += 512) {
            int c = idx / 144, pos = idx - c * 144;
            int r = pos / 12, u = pos - r * 12;
            int gi = i0 + r - 2, gj = j0 + u - 2;
            float v = 0.f;
            if ((unsigned)gi < 64u && (unsigned)gj < 64u)
                v = x[(((b * 256 + cc * 32 + c) << 12) + (gi << 6) + gj)];
            xs[idx] = v;
        }
        __syncthreads();
        for (int c8 = wid; c8 < 32; c8 += 8) {
            const float* xc = xs + c8 * 144 + li * 12 + lj;
            float a0 = 0.f, a1 = 0.f, a2 = 0.f, a3 = 0.f;
#pragma unroll
            for (int dy = 0; dy < 5; dy++) {
#pragma unroll
                for (int dx = 0; dx < 5; dx++) {
                    float xv = xc[dy * 12 + dx];
                    const int k = dy * 5 + dx;
                    a0 += xv * w[k][0];
                    a1 += xv * w[k][1];
                    a2 += xv * w[k][2];
                    a3 += xv * w[k][3];
                }
            }
            int c = cc * 32 + c8;
            float4 o4 = make_float4(a0, a1, a2, a3);
            *(float4*)(out + (((long long)(b * 256 + c)) << 14) + pgl * 4) = o4;
        }
        __syncthreads();
    }
}

extern "C" void kernel_launch(void* const* d_in, const int* in_sizes, int n_in,
                              void* d_out, int out_size, void* d_ws, size_t ws_size,
                              hipStream_t stream) {
    const float* x  = (const float*)d_in[0];
    const float* Wc = (const float*)d_in[1];
    const float* bc = (const float*)d_in[2];
    const float* We = (const float*)d_in[3];
    const float* be = (const float*)d_in[4];
    float* out = (float*)d_out;

    if (ws_size >= (size_t)WS_FLOATS * sizeof(float)) {
        float* ws = (float*)d_ws;
        prep_kernel<<<288, 256, 0, stream>>>(Wc, We, ws);
        compress_kernel<<<1024, 256, 0, stream>>>(x, bc, ws, ws + OFF_FEAT);
        enc_kernel<<<512, 512, 0, stream>>>(be, ws, ws + OFF_WK);
        gather_kernel<<<8192, 256, 0, stream>>>(x, ws, out);
    } else {
        carafe_fused<<<256, 512, 0, stream>>>(x, Wc, bc, We, be, out);
    }
}

// Round 13
// 180.079 us; speedup vs baseline: 1.0601x; 1.0601x over previous
//
#include <hip/hip_runtime.h>

// CARAFE++ (B=4, C=256, H=W=64, SCALE=2, K=5, G=1, MID=64, ENC_OUT=100). FP32 I/O.
// R18: 190.9us REGRESSION. gather b64 parity-dual-copy: conflicts 0 -> 6.55M
//   (O-base 2720 % 32 == 0 -> lane pairs hit same banks, diff addr = serialize;
//   440 LDS cyc/wave vs 400 before). Second failed gather-LDS restructure.
// R19: REVERT gather to R15-exact (16-ch slabs, grid 4096, scalar b32 reads,
//   f32x2 pk-FMA: 43.6us, conflicts 0) — proven local optimum; per-pixel wk
//   pins VGPR so p-reuse can't widen, and b64 trades instrs for conflicts 1:1.
//   enc R16 + compress R14 kept. Ledger: kernels sum ~95-100us; dur_us ~177-190
//   includes ~80us of harness fill/launch overhead we don't control.
//
// ws layout (float offsets):
#define OFF_FEAT 0              // feat [b][pix][m=64]             1,048,576 f
#define OFF_WET  1048576        // W_enc^T [m*9+rs][p*32+kk]          73,728 f
#define OFF_WCT  1122304        // W_comp^T [c][m]                    16,384 f
#define OFF_WK   1138688        // wk2 [p*25+k][b*4096+pix]        1,638,400 f
#define WS_FLOATS 2777088       // = 11,108,352 bytes

using f32x2 = __attribute__((ext_vector_type(2))) float;

// ---------------- prep: weight transposes ----------------
__global__ __launch_bounds__(256) void prep_kernel(
    const float* __restrict__ Wc, const float* __restrict__ We,
    float* __restrict__ ws) {
    int i = blockIdx.x * 256 + threadIdx.x;
    if (i < 16384) {                       // WcT[c*64+m] = Wc[m][c]
        int c = i >> 6, m = i & 63;
        ws[OFF_WCT + i] = Wc[m * 256 + c];
    }
    if (i < 73728) {                       // Wet[(m*9+rs)*128 + p*32 + kk]
        int mrs = i >> 7, rem = i & 127;
        int p = rem >> 5, kk = rem & 31;
        ws[OFF_WET + i] = (kk < 25) ? We[(p * 25 + kk) * 576 + mrs] : 0.f;
    }
}

// ---------------- K1: 1x1 compress conv + relu ----------------
// grid 1024 x 256 thr = 4 waves/block, wave = 4 px, lane = m.
// Per c: 1 coalesced w-load (VGPR) + 1 uniform float4 x-read (SGPR) + 2 pk-FMA.
__global__ __launch_bounds__(256) void compress_kernel(
    const float* __restrict__ x, const float* __restrict__ bc,
    const float* __restrict__ ws, float* __restrict__ feat) {
    int t = threadIdx.x;
    int lane = t & 63;                               // = m
    int px0 = __builtin_amdgcn_readfirstlane((blockIdx.x << 4) + ((t >> 6) << 2));
    int b = px0 >> 12, pl = px0 & 4095;
    const float* wct = ws + OFF_WCT;                 // [c][64 m]
    const float* xw = x + (((size_t)(b * 256)) << 12) + pl;   // wave-uniform
    f32x2 a01 = {0.f, 0.f}, a23 = {0.f, 0.f};
#pragma unroll 4
    for (int c = 0; c < 256; c++) {
        float w = wct[(c << 6) + lane];              // coalesced, L2-hot
        const float4 xv = *(const float4*)(xw + ((size_t)c << 12));  // uniform
        a01 += (f32x2){xv.x, xv.y} * w;
        a23 += (f32x2){xv.z, xv.w} * w;
    }
    float bv = bc[lane];
    float v0 = a01.x + bv, v1 = a01.y + bv, v2 = a23.x + bv, v3 = a23.y + bv;
    float* fp = feat + (((size_t)((b << 12) + pl)) << 6) + lane;  // [pix][m]
    fp[0]   = v0 > 0.f ? v0 : 0.f;                   // coalesced over m
    fp[64]  = v1 > 0.f ? v1 : 0.f;
    fp[128] = v2 > 0.f ? v2 : 0.f;
    fp[192] = v3 > 0.f ? v3 : 0.f;
}

// ---------------- K2: 3x3 enc conv + bias + softmax(25) ----------------
// grid 512 = (b x 8x8 tile) x 2 p-pairs. 512 thr = 64 px x (2pp x 2kg x 2mg).
// q=16 kk-slice (2x s_load-wide), HALF the m per thread -> half the ds_reads.
// mg partials merged in LDS (stride-65, conflict-free); bias at merge.
__global__ __launch_bounds__(512, 4) void enc_kernel(
    const float* __restrict__ be, const float* __restrict__ ws,
    float* __restrict__ wkout) {
    __shared__ float fs[4224];   // halo [32m][121]=3872 / merged logits [64px][65]
    int t = threadIdx.x;
    int blk = blockIdx.x;
    int tile = blk >> 1, ph2 = blk & 1;    // p-pair index
    int b = tile >> 6, t6 = tile & 63;
    int i0 = (t6 >> 3) << 3, j0 = (t6 & 7) << 3;
    int pix = t & 63;
    int li = pix >> 3, lj = pix & 7;
    int g = __builtin_amdgcn_readfirstlane(t >> 6);  // 0..7, wave-uniform
    int pp = (g >> 2) & 1;                           // p within pair
    int kg = (g >> 1) & 1;                           // kk half: k0 = kg*16
    int mg = g & 1;                                  // m half within phase
    int p = (ph2 << 1) | pp;
    int k0 = kg << 4;
    const float* feat = ws + OFF_FEAT;               // [b][pix][64 m]
    const float* wet = ws + OFF_WET + p * 32 + k0;   // uniform, 64B-aligned

    f32x2 acc2[8];
#pragma unroll
    for (int q = 0; q < 8; q++) acc2[q] = (f32x2){0.f, 0.f};

    for (int phase = 0; phase < 2; phase++) {
        int mb = phase << 5;
        for (int idx = t; idx < 3200; idx += 512) {  // stage 32-m halo (0-padded)
            int m = idx & 31, pos = idx >> 5;        // lanes: consecutive m
            int r = pos / 10, s = pos - r * 10;
            int gi = i0 + r - 1, gj = j0 + s - 1;
            float v = 0.f;
            if ((unsigned)gi < 64u && (unsigned)gj < 64u)
                v = feat[(((size_t)((b << 12) + (gi << 6) + gj)) << 6) + mb + m];
            fs[m * 121 + r * 12 + s] = v;            // stride-121: conflict-free
        }
        __syncthreads();

        int m0 = mg << 4;                            // this thread's m half
#pragma unroll 2
        for (int m = m0; m < m0 + 16; m++) {
            const float* fb = fs + m * 121 + li * 12 + lj;
            float f9[9];
#pragma unroll
            for (int r = 0; r < 3; r++)
#pragma unroll
                for (int s = 0; s < 3; s++) f9[r * 3 + s] = fb[r * 12 + s];
            const float* wrow = wet + (mb + m) * 1152;   // uniform -> s_load_dwordx16
#pragma unroll
            for (int rs = 0; rs < 9; rs++) {
                float f = f9[rs];
                const f32x2* w2 = (const f32x2*)(wrow + rs * 128);  // 16 kk slice
#pragma unroll
                for (int q = 0; q < 8; q++) acc2[q] += f * w2[q];
            }
        }
        __syncthreads();                             // reads done before re-stage
    }

    // merge mg halves: region fs[pix*65 + pp*32 + kg*16 + q] (stride 65 = c-free)
    int red = pix * 65 + (pp << 5) + k0;
    if (mg == 0) {
#pragma unroll
        for (int q = 0; q < 8; q++) {
            fs[red + 2 * q]     = acc2[q].x;
            fs[red + 2 * q + 1] = acc2[q].y;
        }
    }
    __syncthreads();
    if (mg == 1) {                                   // total + bias (k>=25 garbage)
#pragma unroll
        for (int q = 0; q < 8; q++) {
            int k = k0 + 2 * q;
            if (k < 25)     fs[red + 2 * q]     += acc2[q].x + be[p * 25 + k];
            if (k + 1 < 25) fs[red + 2 * q + 1] += acc2[q].y + be[p * 25 + k + 1];
        }
    }
    __syncthreads();

    if (t < 128) {                                   // softmax: thread = (pp, pixel)
        int sp = t >> 6, spx = t & 63;
        const float* lg = fs + spx * 65 + (sp << 5); // merged row, k = 0..24 direct
        float sv[25], mx = -1e30f;
#pragma unroll
        for (int k = 0; k < 25; k++) { sv[k] = lg[k]; mx = fmaxf(mx, sv[k]); }
        float s = 0.f;
#pragma unroll
        for (int k = 0; k < 25; k++) { sv[k] = __expf(sv[k] - mx); s += sv[k]; }
        float inv = 1.f / s;
        int preal = (ph2 << 1) | sp;
        int pgl = ((i0 + (spx >> 3)) << 6) + j0 + (spx & 7);
        float* wp = wkout + (preal * 25) * 16384 + (b << 12) + pgl;
#pragma unroll
        for (int k = 0; k < 25; k++) wp[k * 16384] = sv[k] * inv;  // coalesced
    }
}

// ---------------- K3: gather + pixel rearrange ----------------
// grid 4096 = (b*64+i)*16 + cc(16 ch). 256 thr = 64 j x (2 p-pairs x 2 c-halves).
// Inner: per xv 1 pk-FMA (p-pair packed in f32x2 w01[25]). R15-exact (proven).
__global__ __launch_bounds__(256) void gather_kernel(
    const float* __restrict__ x, const float* __restrict__ ws,
    float* __restrict__ out) {
    __shared__ float xs[16 * 5 * 68];                // 21.76 KB
    int t = threadIdx.x;
    int blk = blockIdx.x;
    int cc = blk & 15;
    int bi = blk >> 4;
    int b = bi >> 6, i = bi & 63;
    int j = t & 63;
    int g = t >> 6;
    int ph = g >> 1, ch = g & 1;

    // coalesced wk loads: wk2[(p*25+k)*16384 + b*4096 + i*64 + j]
    f32x2 w01[25];
    {
        const float* wp = ws + OFF_WK + (ph * 50) * 16384 + (b << 12) + (i << 6) + j;
#pragma unroll
        for (int k = 0; k < 25; k++) {
            w01[k].x = wp[k * 16384];
            w01[k].y = wp[(25 + k) * 16384];
        }
    }

    // div-free-ish staging: aligned 64-float row core + guarded zero pads.
    {
        int lane = t & 63, cd0 = t >> 6;             // (c,dy) pairs, 4 at a time
        for (int cd = cd0; cd < 80; cd += 4) {
            int c = cd / 5, dy = cd - c * 5;
            int gi = i - 2 + dy;
            float v = 0.f;
            if ((unsigned)gi < 64u)
                v = x[((b * 256 + (cc << 4) + c) << 12) + (gi << 6) + lane];
            float* row = xs + cd * 68;
            row[2 + lane] = v;
            if (lane < 2) row[lane] = 0.f;           // gj < 0 pad
            if (lane >= 62) row[lane + 4] = 0.f;     // gj >= 64 pad
        }
    }
    __syncthreads();

    for (int c2 = ch; c2 < 16; c2 += 2) {
        const float* xb = xs + (c2 * 5) * 68 + j;    // u = j+dx -> gj = j+dx-2
        f32x2 a2 = {0.f, 0.f};
#pragma unroll
        for (int dy = 0; dy < 5; dy++) {
#pragma unroll
            for (int dx = 0; dx < 5; dx++) {
                float xv = xb[dy * 68 + dx];
                a2 += xv * w01[dy * 5 + dx];
            }
        }
        int c = (cc << 4) + c2;
        *(float2*)(out + (((b * 256 + c) << 12) + (i << 6) + j) * 4 + ph * 2) =
            make_float2(a2.x, a2.y);
    }
}

// ---------------- fallback: round-3 fused kernel (correct, slow) ----------------
__global__ __launch_bounds__(512) void carafe_fused(
    const float* __restrict__ x, const float* __restrict__ Wc,
    const float* __restrict__ bc, const float* __restrict__ We,
    const float* __restrict__ be, float* __restrict__ out) {
    __shared__ float xs[32 * 144];
    __shared__ float fw[6656];
    __shared__ float wst[3600];
    const int t = threadIdx.x;
    const int blk = blockIdx.x;
    const int b = blk >> 6, tile = blk & 63;
    const int i0 = (tile >> 3) << 3, j0 = (tile & 7) << 3;
    const int wid = t >> 6, pix = t & 63;
    const int li = pix >> 3, lj = pix & 7;
    float facc[13];
#pragma unroll
    for (int q = 0; q < 13; q++) facc[q] = 0.f;
    for (int cc = 0; cc < 8; cc++) {
        for (int idx = t; idx < 32 * 144; idx += 512) {
            int c = idx / 144, pos = idx - c * 144;
            int r = pos / 12, u = pos - r * 12;
            int gi = i0 + r - 2, gj = j0 + u - 2;
            float v = 0.f;
            if ((unsigned)gi < 64u && (unsigned)gj < 64u)
                v = x[(((b * 256 + cc * 32 + c) << 12) + (gi << 6) + gj)];
            xs[idx] = v;
        }
        __syncthreads();
#pragma unroll
        for (int q = 0; q < 13; q++) {
            int idx = q * 512 + t;
            if (idx < 6400) {
                int m = idx / 100, pos = idx - m * 100;
                int fi = pos / 10, fj = pos - fi * 10;
                int tp = (fi + 1) * 12 + fj + 1;
                const float* wr = Wc + m * 256 + cc * 32;
                float a = facc[q];
                for (int c = 0; c < 32; c++) a += xs[c * 144 + tp] * wr[c];
                facc[q] = a;
            }
        }
        __syncthreads();
    }
#pragma unroll
    for (int q = 0; q < 13; q++) {
        int idx = q * 512 + t;
        if (idx < 6400) {
            int m = idx / 100, pos = idx - m * 100;
            int fi = pos / 10, fj = pos - fi * 10;
            int gi = i0 + fi - 1, gj = j0 + fj - 1;
            float v = facc[q] + bc[m];
            v = v > 0.f ? v : 0.f;
            if ((unsigned)gi >= 64u || (unsigned)gj >= 64u) v = 0.f;
            fw[idx] = v;
        }
    }
    float acc[13];
#pragma unroll
    for (int q = 0; q < 13; q++) acc[q] = 0.f;
    for (int mb = 0; mb < 16; mb++) {
        for (int idx = t; idx < 3600; idx += 512) {
            int mm = idx / 900, rem = idx - mm * 900;
            int o = rem / 9, rs = rem - o * 9;
            wst[idx] = We[o * 576 + (mb * 4 + mm) * 9 + rs];
        }
        __syncthreads();
#pragma unroll
        for (int mm = 0; mm < 4; mm++) {
            const float* fb = fw + (mb * 4 + mm) * 100 + li * 10 + lj;
            float f9[9];
#pragma unroll
            for (int r = 0; r < 3; r++)
#pragma unroll
                for (int s = 0; s < 3; s++) f9[r * 3 + s] = fb[r * 10 + s];
#pragma unroll
            for (int q = 0; q < 13; q++) {
                int o = q * 8 + wid;
                if (o < 100) {
                    const float* wr = wst + mm * 900 + o * 9;
                    float a = acc[q];
#pragma unroll
                    for (int rs = 0; rs < 9; rs++) a += f9[rs] * wr[rs];
                    acc[q] = a;
                }
            }
        }
        __syncthreads();
    }
#pragma unroll
    for (int q = 0; q < 13; q++) {
        int o = q * 8 + wid;
        if (o < 100) fw[pix * 104 + o] = acc[q];
    }
    __syncthreads();
    float sv[25];
    float inv = 0.f;
    const int sp = t >> 6, spx = t & 63;
    const bool act = (t < 256);
    if (act) {
        float mx = -1e30f;
#pragma unroll
        for (int k = 0; k < 25; k++) {
            sv[k] = fw[spx * 104 + sp * 25 + k] + be[sp * 25 + k];
            mx = fmaxf(mx, sv[k]);
        }
        float s = 0.f;
#pragma unroll
        for (int k = 0; k < 25; k++) { sv[k] = __expf(sv[k] - mx); s += sv[k]; }
        inv = 1.f / s;
    }
    __syncthreads();
    if (act) {
#pragma unroll
        for (int k = 0; k < 25; k++) fw[spx * 104 + k * 4 + sp] = sv[k] * inv;
    }
    __syncthreads();
    float w[25][4];
    const float4* wp = (const float4*)(fw + pix * 104);
#pragma unroll
    for (int k = 0; k < 25; k++) {
        float4 ww = wp[k];
        w[k][0] = ww.x; w[k][1] = ww.y; w[k][2] = ww.z; w[k][3] = ww.w;
    }
    const int pgl = ((i0 + li) << 6) + (j0 + lj);
    for (int cc = 0; cc < 8; cc++) {
        for (int idx = t; idx < 32 * 144; idx += 512) {
            int c = idx / 144, pos = idx - c * 144;
            int r = pos / 12, u = pos - r * 12;
            int gi = i0 + r - 2, gj = j0 + u - 2;
            float v = 0.f;
            if ((unsigned)gi < 64u && (unsigned)gj < 64u)
                v = x[(((b * 256 + cc * 32 + c) << 12) + (gi << 6) + gj)];
            xs[idx] = v;
        }
        __syncthreads();
        for (int c8 = wid; c8 < 32; c8 += 8) {
            const float* xc = xs + c8 * 144 + li * 12 + lj;
            float a0 = 0.f, a1 = 0.f, a2 = 0.f, a3 = 0.f;
#pragma unroll
            for (int dy = 0; dy < 5; dy++) {
#pragma unroll
                for (int dx = 0; dx < 5; dx++) {
                    float xv = xc[dy * 12 + dx];
                    const int k = dy * 5 + dx;
                    a0 += xv * w[k][0];
                    a1 += xv * w[k][1];
                    a2 += xv * w[k][2];
                    a3 += xv * w[k][3];
                }
            }
            int c = cc * 32 + c8;
            float4 o4 = make_float4(a0, a1, a2, a3);
            *(float4*)(out + (((long long)(b * 256 + c)) << 14) + pgl * 4) = o4;
        }
        __syncthreads();
    }
}

extern "C" void kernel_launch(void* const* d_in, const int* in_sizes, int n_in,
                              void* d_out, int out_size, void* d_ws, size_t ws_size,
                              hipStream_t stream) {
    const float* x  = (const float*)d_in[0];
    const float* Wc = (const float*)d_in[1];
    const float* bc = (const float*)d_in[2];
    const float* We = (const float*)d_in[3];
    const float* be = (const float*)d_in[4];
    float* out = (float*)d_out;

    if (ws_size >= (size_t)WS_FLOATS * sizeof(float)) {
        float* ws = (float*)d_ws;
        prep_kernel<<<288, 256, 0, stream>>>(Wc, We, ws);
        compress_kernel<<<1024, 256, 0, stream>>>(x, bc, ws, ws + OFF_FEAT);
        enc_kernel<<<512, 512, 0, stream>>>(be, ws, ws + OFF_WK);
        gather_kernel<<<4096, 256, 0, stream>>>(x, ws, out);
    } else {
        carafe_fused<<<256, 512, 0, stream>>>(x, Wc, bc, We, be, out);
    }
}